// Round 4
// baseline (210.578 us; speedup 1.0000x reference)
//
#include <hip/hip_runtime.h>

// B=2, N=2048, DIM=1024, HEADS=16, DHEAD=64, INNER=1024. fp32 in/out.
// prep -> qkv GEMM (16x16x32, gld16, XOR-swizzle, XCD supertile; K/V written
// in attn fragment-order tiles) -> attn v8 (LDS-free main loop, qt=2,
// TRIPLE-buffered K/V reg prefetch: distance-2 covers ~800cyc L2/HBM
// latency at 2 waves/SIMD; ~248 regs, just under the 256 2-wave cliff) ->
// out GEMM (XCD supertile). similarity ignored: softmax row-const no-op.
// (Resubmit of R3 kernel: bench failed on infra, not kernel.)

typedef __attribute__((ext_vector_type(8))) short short8;
typedef __attribute__((ext_vector_type(4))) float float4_;
typedef __attribute__((ext_vector_type(16))) float floatx16;
typedef __attribute__((ext_vector_type(4))) unsigned short ushort4_;
typedef __attribute__((ext_vector_type(4))) unsigned int uint4_;

#define MFMA(a, b, c) __builtin_amdgcn_mfma_f32_16x16x32_bf16((a), (b), (c), 0, 0, 0)
#define MFMA32(a, b, c) __builtin_amdgcn_mfma_f32_32x32x16_bf16((a), (b), (c), 0, 0, 0)

static __device__ __forceinline__ unsigned short f2bf(float f) {
    union { float f; unsigned int u; } v; v.f = f;
    unsigned int r = v.u + 0x7FFFu + ((v.u >> 16) & 1u);  // RNE
    return (unsigned short)(r >> 16);
}

static __device__ __forceinline__ void gld16(const void* g, void* l) {
    __builtin_amdgcn_global_load_lds(
        (__attribute__((address_space(1))) void*)(g),
        (__attribute__((address_space(3))) void*)(l), 16, 0, 0);
}

// ---------------------------------------------------------------------------
// K0 prep: blocks 0..1023 transpose+convert weights; 1024..1535 convert X.
// ---------------------------------------------------------------------------
__global__ __launch_bounds__(256) void prep(
    const float* __restrict__ X, const float* __restrict__ Wq,
    const float* __restrict__ Wkv, const float* __restrict__ Wo,
    unsigned short* __restrict__ xb, unsigned short* __restrict__ Wt,
    unsigned short* __restrict__ Wot)
{
    const int bid = blockIdx.x, t = threadIdx.x;
    if (bid >= 1024) {
        const int b = bid - 1024;
        const float4_* src = (const float4_*)X;
        ushort4_* dst = (ushort4_*)xb;
        #pragma unroll
        for (int g = 0; g < 8; ++g) {
            const int idx = b * 2048 + g * 256 + t;
            float4_ v = src[idx];
            ushort4_ o;
            o[0] = f2bf(v[0]); o[1] = f2bf(v[1]);
            o[2] = f2bf(v[2]); o[3] = f2bf(v[3]);
            dst[idx] = o;
        }
        return;
    }
    __shared__ float tile[64][65];
    const float* src; unsigned short* dst; int N, kt, nt, drow0;
    if (bid < 256)      { src = Wq;  N = 1024; kt = bid & 15;       nt = bid >> 4;       dst = Wt;  drow0 = nt * 64; }
    else if (bid < 768) { src = Wkv; N = 2048; kt = (bid-256) & 15; nt = (bid-256) >> 4; dst = Wt;  drow0 = 1024 + nt * 64; }
    else                { src = Wo;  N = 1024; kt = (bid-768) & 15; nt = (bid-768) >> 4; dst = Wot; drow0 = nt * 64; }
    const int k0 = kt * 64, n0 = nt * 64;
    const int r0 = t >> 6, c = t & 63;
    #pragma unroll
    for (int i = 0; i < 16; ++i) {
        const int r = i * 4 + r0;
        tile[r][c] = src[(size_t)(k0 + r) * N + n0 + c];
    }
    __syncthreads();
    #pragma unroll
    for (int i = 0; i < 16; ++i) {
        const int rn = i * 4 + r0;
        dst[(size_t)(drow0 + rn) * 1024 + k0 + c] = f2bf(tile[c][rn]);
    }
}

// ---------------------------------------------------------------------------
// K1: QKV = xb @ Wt^T. 128x128 tile, gld16 + XOR swizzle. XCD supertile.
// K output re-tiled for attn fragment loads:
//   kt[(key>>5)*2048 + (d>>3)*256 + (key&31)*8 + (d&7)]   (per bh, 131072 sh)
// V output re-tiled:
//   vt[(key>>3)*512 + d*8 + (key&7)]                      (per bh, 131072 sh)
// ---------------------------------------------------------------------------
__global__ __launch_bounds__(256) void qkv_gemm2(
    const unsigned short* __restrict__ xb, const unsigned short* __restrict__ Wt,
    unsigned short* __restrict__ q_ws, unsigned short* __restrict__ k_ws,
    unsigned short* __restrict__ vt_ws)
{
    __shared__ unsigned short As[128 * 64];
    __shared__ unsigned short Bs[128 * 64];
    const int t = threadIdx.x, wave = t >> 6, lane = t & 63;
    const int L = lane & 15, quad = lane >> 4;
    const int xcd = blockIdx.x & 7, idx = blockIdx.x >> 3;
    const int mb = (xcd >> 1) * 8 + (idx & 7);
    const int nb = (xcd & 1) * 12 + (idx >> 3);
    const int m0 = mb * 128, n0 = nb * 128;
    const int wr = wave >> 1, wc = wave & 1;

    float4_ z = {0.f, 0.f, 0.f, 0.f};
    float4_ acc[4][4];
    #pragma unroll
    for (int i = 0; i < 4; ++i)
        #pragma unroll
        for (int j = 0; j < 4; ++j) acc[i][j] = z;

    const unsigned short* gA[4]; const unsigned short* gB[4];
    unsigned short* lA[4]; unsigned short* lB[4];
    #pragma unroll
    for (int j = 0; j < 4; ++j) {
        const int cid = wave * 256 + j * 64 + lane;
        const int row = cid >> 3, pc = cid & 7;
        const int lch = pc ^ (row & 7);
        gA[j] = xb + (size_t)(m0 + row) * 1024 + lch * 8;
        gB[j] = Wt + (size_t)(n0 + row) * 1024 + lch * 8;
        lA[j] = As + wave * 2048 + j * 512;
        lB[j] = Bs + wave * 2048 + j * 512;
    }

    for (int kc = 0; kc < 1024; kc += 64) {
        #pragma unroll
        for (int j = 0; j < 4; ++j) {
            gld16(gA[j] + kc, lA[j]);
            gld16(gB[j] + kc, lB[j]);
        }
        __syncthreads();
        #pragma unroll
        for (int ks = 0; ks < 2; ++ks) {
            short8 af[4], bfr[4];
            #pragma unroll
            for (int mt = 0; mt < 4; ++mt) {
                const int rl = wr * 64 + mt * 16 + L;
                af[mt] = *(const short8*)(As + rl * 64 + (((ks * 4 + quad) ^ (L & 7)) << 3));
            }
            #pragma unroll
            for (int nt = 0; nt < 4; ++nt) {
                const int rl = wc * 64 + nt * 16 + L;
                bfr[nt] = *(const short8*)(Bs + rl * 64 + (((ks * 4 + quad) ^ (L & 7)) << 3));
            }
            #pragma unroll
            for (int mt = 0; mt < 4; ++mt)
                #pragma unroll
                for (int nt = 0; nt < 4; ++nt)
                    acc[mt][nt] = MFMA(af[mt], bfr[nt], acc[mt][nt]);
        }
        __syncthreads();
    }

    const int b = m0 >> 11;
    const int type = n0 >> 10;  // 0=Q, 1=K, 2=V
    #pragma unroll
    for (int mt = 0; mt < 4; ++mt) {
        const int m = (m0 & 2047) + wr * 64 + mt * 16 + quad * 4;
        #pragma unroll
        for (int nt = 0; nt < 4; ++nt) {
            const int cl = (n0 & 1023) + wc * 64 + nt * 16 + L;
            const int h = cl >> 6, d = cl & 63;
            float4_ v = acc[mt][nt];
            if (type == 0) {
                // fold 0.125 softmax scale and log2(e): exp(x)=exp2(x*log2e)
                unsigned short* p = q_ws + ((size_t)(b * 16 + h) * 2048 + m) * 64 + d;
                #pragma unroll
                for (int r = 0; r < 4; ++r) p[(size_t)r * 64] = f2bf(v[r] * 0.18033688011f);
            } else if (type == 1) {
                // fragment-order K tile (key advances by r: stride 8 shorts)
                unsigned short* p = k_ws + (size_t)(b * 16 + h) * 131072
                    + (m >> 5) * 2048 + (d >> 3) * 256 + (m & 31) * 8 + (d & 7);
                #pragma unroll
                for (int r = 0; r < 4; ++r) p[r * 8] = f2bf(v[r]);
            } else {
                // fragment-order V tile: keys m..m+3 contiguous at fixed d
                ushort4_ pk;
                pk[0] = f2bf(v[0]); pk[1] = f2bf(v[1]);
                pk[2] = f2bf(v[2]); pk[3] = f2bf(v[3]);
                *(ushort4_*)(vt_ws + (size_t)(b * 16 + h) * 131072
                    + (m >> 3) * 512 + d * 8 + (m & 7)) = pk;
            }
        }
    }
}

// ---------------------------------------------------------------------------
// K2 v8: LDS-free flash attention, triple-buffered. 1024 blocks x 128
// threads. Each block: one (bh, 64 q-rows); wave w owns keys [w*1024,
// w*1024+1024) -> no barriers in main loop (no running max => partials add
// exactly). Triple K/V reg buffers give prefetch distance 2 (~800 cyc of
// compute) to cover L2/HBM latency at 2 waves/SIMD. ~248 VGPR+AGPR: just
// under the 256 two-wave cliff (v6's 280 spilled). pi (bit2<->bit3 of
// key-row) applied at K read (verified mapping v5/v6/v7).
// ---------------------------------------------------------------------------
#define LOADT(k0_, k1_, k2_, k3_, v00_, v10_, v01_, v11_, IT) do {            \
    const unsigned short* kp_ = kbase + (IT) * 2048;                          \
    const unsigned short* vp_ = vbase + (IT) * 2048;                          \
    k0_ = *(const short8*)(kp_);        k1_ = *(const short8*)(kp_ + 512);    \
    k2_ = *(const short8*)(kp_ + 1024); k3_ = *(const short8*)(kp_ + 1536);   \
    v00_ = *(const short8*)(vp_);        v10_ = *(const short8*)(vp_ + 1024); \
    v01_ = *(const short8*)(vp_ + 256);  v11_ = *(const short8*)(vp_ + 1280); \
} while (0)

#define COMPT(k0_, k1_, k2_, k3_, v00_, v10_, v01_, v11_) do {                \
    _Pragma("unroll")                                                         \
    for (int qt = 0; qt < 2; ++qt) {                                          \
        floatx16 s;                                                           \
        _Pragma("unroll")                                                     \
        for (int r = 0; r < 16; ++r) s[r] = 0.f;                              \
        s = MFMA32(k0_, qf[qt][0], s);                                        \
        s = MFMA32(k1_, qf[qt][1], s);                                        \
        s = MFMA32(k2_, qf[qt][2], s);                                        \
        s = MFMA32(k3_, qf[qt][3], s);                                        \
        unsigned int pk[8];                                                   \
        float ls_ = 0.f;                                                      \
        _Pragma("unroll")                                                     \
        for (int d = 0; d < 8; ++d) {                                         \
            union { float f; unsigned int u; } a_, b_;                        \
            a_.f = __builtin_amdgcn_exp2f(s[2 * d]);                          \
            b_.f = __builtin_amdgcn_exp2f(s[2 * d + 1]);                      \
            ls_ += a_.f + b_.f;                                               \
            pk[d] = __builtin_amdgcn_perm(b_.u, a_.u, 0x07060302u);           \
        }                                                                     \
        lsum[qt] += ls_;                                                      \
        uint4_ w0_, w1_;                                                      \
        w0_[0] = pk[0]; w0_[1] = pk[1]; w0_[2] = pk[2]; w0_[3] = pk[3];       \
        w1_[0] = pk[4]; w1_[1] = pk[5]; w1_[2] = pk[6]; w1_[3] = pk[7];       \
        short8 pa0 = *(short8*)&w0_, pa1 = *(short8*)&w1_;                    \
        o[qt][0] = MFMA32(pa0, v00_, o[qt][0]);                               \
        o[qt][0] = MFMA32(pa1, v10_, o[qt][0]);                               \
        o[qt][1] = MFMA32(pa0, v01_, o[qt][1]);                               \
        o[qt][1] = MFMA32(pa1, v11_, o[qt][1]);                               \
    }                                                                         \
} while (0)

__global__ __launch_bounds__(128, 2) void attn_fwd8(
    const unsigned short* __restrict__ q_ws,
    const unsigned short* __restrict__ k_ws,
    const unsigned short* __restrict__ vt_ws,
    unsigned short* __restrict__ o2)
{
    __shared__ float cbuf[2][2048];   // 16 KB: cross-wave O combine
    __shared__ float lsd[2][2][32];   // row-sum totals per wave/qt
    const int t = threadIdx.x, wave = t >> 6, lane = t & 63;
    const int l32 = lane & 31, hi = lane >> 5;
    const int xcd = blockIdx.x & 7, loc = blockIdx.x >> 3;
    const int bh = xcd * 4 + (loc >> 5);
    const int qb = loc & 31;   // 64-row q tile

    // Q fragments: 64 q-rows in registers, 8 short8 (32 VGPRs).
    short8 qf[2][4];
    #pragma unroll
    for (int qt = 0; qt < 2; ++qt) {
        const unsigned short* Qp = q_ws
            + ((size_t)(bh * 2048 + qb * 64 + qt * 32 + l32)) * 64 + hi * 8;
        #pragma unroll
        for (int ks = 0; ks < 4; ++ks)
            qf[qt][ks] = *(const short8*)(Qp + ks * 16);
    }

    // pi: swap bits 2,3 of key-row (A-operand k-map compensation, from v5).
    const int piRow = (l32 & ~12) | ((l32 & 4) << 1) | ((l32 & 8) >> 1);
    const unsigned short* kbase = k_ws + (size_t)bh * 131072
        + wave * 65536 + hi * 256 + piRow * 8;
    const unsigned short* vbase = vt_ws + (size_t)bh * 131072
        + wave * 65536 + hi * 512 + l32 * 8;

    floatx16 o[2][2];
    float lsum[2] = {0.f, 0.f};
    #pragma unroll
    for (int qt = 0; qt < 2; ++qt)
        #pragma unroll
        for (int r = 0; r < 16; ++r) { o[qt][0][r] = 0.f; o[qt][1][r] = 0.f; }

    short8 kA0, kA1, kA2, kA3, vA00, vA10, vA01, vA11;
    short8 kB0, kB1, kB2, kB3, vB00, vB10, vB01, vB11;
    short8 kC0, kC1, kC2, kC3, vC00, vC10, vC01, vC11;
    LOADT(kA0, kA1, kA2, kA3, vA00, vA10, vA01, vA11, 0);
    LOADT(kB0, kB1, kB2, kB3, vB00, vB10, vB01, vB11, 1);

    #pragma unroll 1
    for (int it = 0; it < 30; it += 3) {
        LOADT(kC0, kC1, kC2, kC3, vC00, vC10, vC01, vC11, it + 2);
        COMPT(kA0, kA1, kA2, kA3, vA00, vA10, vA01, vA11);
        LOADT(kA0, kA1, kA2, kA3, vA00, vA10, vA01, vA11, it + 3);
        COMPT(kB0, kB1, kB2, kB3, vB00, vB10, vB01, vB11);
        LOADT(kB0, kB1, kB2, kB3, vB00, vB10, vB01, vB11, it + 4);
        COMPT(kC0, kC1, kC2, kC3, vC00, vC10, vC01, vC11);
    }
    // tail: A holds it=30, B holds it=31
    COMPT(kA0, kA1, kA2, kA3, vA00, vA10, vA01, vA11);
    COMPT(kB0, kB1, kB2, kB3, vB00, vB10, vB01, vB11);

    // Row-sum totals (sum over both key-halves held by lanes l32, l32+32).
    #pragma unroll
    for (int qt = 0; qt < 2; ++qt) {
        float ltot = lsum[qt] + __shfl_xor(lsum[qt], 32);
        lsd[wave][qt][l32] = ltot;
    }

    // Cross-wave combine: wave w owns qt==w, donates qt==w^1.
    const int qtd = wave ^ 1;
    float* myb = cbuf[wave];
    #pragma unroll
    for (int r = 0; r < 16; ++r) {
        myb[r * 64 + lane]        = o[qtd][0][r];
        myb[(16 + r) * 64 + lane] = o[qtd][1][r];
    }
    __syncthreads();
    const float* otb = cbuf[wave ^ 1];
    const int qto = wave;
    const int b = bh >> 4, h = bh & 15;
    unsigned short* obase = o2 + ((size_t)(b * 2048 + qb * 64)) * 1024 + h * 64;
    #pragma unroll
    for (int r = 0; r < 16; ++r) {
        const int rowloc = (r & 3) + 8 * (r >> 2) + 4 * hi;
        const float o0v = o[qto][0][r] + otb[r * 64 + lane];
        const float o1v = o[qto][1][r] + otb[(16 + r) * 64 + lane];
        const float iv = 1.0f / (lsd[0][qto][rowloc] + lsd[1][qto][rowloc]);
        const int row = qto * 32 + rowloc;
        obase[(size_t)row * 1024 + l32]      = f2bf(o0v * iv);
        obase[(size_t)row * 1024 + 32 + l32] = f2bf(o1v * iv);
    }
}

// ---------------------------------------------------------------------------
// K3: Out = o2 @ Wot^T + bo (fp32 out). 128x64 tile. XCD supertile.
// ---------------------------------------------------------------------------
__global__ __launch_bounds__(256) void out_gemm2(
    const unsigned short* __restrict__ o2, const unsigned short* __restrict__ Wot,
    const float* __restrict__ bo, float* __restrict__ Out)
{
    __shared__ unsigned short As[128 * 64];
    __shared__ unsigned short Bs[64 * 64];
    const int t = threadIdx.x, wave = t >> 6, lane = t & 63;
    const int L = lane & 15, quad = lane >> 4;
    const int xcd = blockIdx.x & 7, idx = blockIdx.x >> 3;
    const int mb = (xcd >> 1) * 8 + (idx & 7);
    const int nb = (xcd & 1) * 8 + (idx >> 3);
    const int m0 = mb * 128, n0 = nb * 64;
    const int wr = wave >> 1, wc = wave & 1;

    float4_ z = {0.f, 0.f, 0.f, 0.f};
    float4_ acc[4][2];
    #pragma unroll
    for (int i = 0; i < 4; ++i)
        #pragma unroll
        for (int j = 0; j < 2; ++j) acc[i][j] = z;

    const unsigned short* gA[4]; unsigned short* lA[4];
    #pragma unroll
    for (int j = 0; j < 4; ++j) {
        const int cid = wave * 256 + j * 64 + lane;
        const int row = cid >> 3, pc = cid & 7;
        gA[j] = o2 + (size_t)(m0 + row) * 1024 + (pc ^ (row & 7)) * 8;
        lA[j] = As + wave * 2048 + j * 512;
    }
    const unsigned short* gB[2]; unsigned short* lB[2];
    #pragma unroll
    for (int j = 0; j < 2; ++j) {
        const int cid = wave * 128 + j * 64 + lane;
        const int row = cid >> 3, pc = cid & 7;
        gB[j] = Wot + (size_t)(n0 + row) * 1024 + (pc ^ (row & 7)) * 8;
        lB[j] = Bs + wave * 1024 + j * 512;
    }

    for (int kc = 0; kc < 1024; kc += 64) {
        #pragma unroll
        for (int j = 0; j < 4; ++j) gld16(gA[j] + kc, lA[j]);
        #pragma unroll
        for (int j = 0; j < 2; ++j) gld16(gB[j] + kc, lB[j]);
        __syncthreads();
        #pragma unroll
        for (int ks = 0; ks < 2; ++ks) {
            short8 af[4], bfr[2];
            #pragma unroll
            for (int mt = 0; mt < 4; ++mt) {
                const int rl = wr * 64 + mt * 16 + L;
                af[mt] = *(const short8*)(As + rl * 64 + (((ks * 4 + quad) ^ (L & 7)) << 3));
            }
            #pragma unroll
            for (int nt = 0; nt < 2; ++nt) {
                const int rl = wc * 32 + nt * 16 + L;
                bfr[nt] = *(const short8*)(Bs + rl * 64 + (((ks * 4 + quad) ^ (L & 7)) << 3));
            }
            #pragma unroll
            for (int mt = 0; mt < 4; ++mt)
                #pragma unroll
                for (int nt = 0; nt < 2; ++nt)
                    acc[mt][nt] = MFMA(af[mt], bfr[nt], acc[mt][nt]);
        }
        __syncthreads();
    }

    #pragma unroll
    for (int mt = 0; mt < 4; ++mt) {
        const int m = m0 + wr * 64 + mt * 16 + quad * 4;
        #pragma unroll
        for (int nt = 0; nt < 2; ++nt) {
            const int c = n0 + wc * 32 + nt * 16 + L;
            const float bias = bo[c];
            #pragma unroll
            for (int r = 0; r < 4; ++r)
                Out[(size_t)(m + r) * 1024 + c] = acc[mt][nt][r] + bias;
        }
    }
}

// ---------------------------------------------------------------------------
extern "C" void kernel_launch(void* const* d_in, const int* in_sizes, int n_in,
                              void* d_out, int out_size, void* d_ws, size_t ws_size,
                              hipStream_t stream) {
    const float* x   = (const float*)d_in[0];
    // d_in[1] = similarity: softmax no-op, ignored.
    const float* Wq  = (const float*)d_in[2];
    const float* Wkv = (const float*)d_in[3];
    const float* Wo  = (const float*)d_in[4];
    const float* bo  = (const float*)d_in[5];
    float* out = (float*)d_out;

    char* ws = (char*)d_ws;
    const size_t MB = 1024 * 1024;
    unsigned short* xb   = (unsigned short*)(ws);            // 8 MB; reused as o2
    unsigned short* o2   = xb;                               // alias (xb dead after K1)
    unsigned short* Wt   = (unsigned short*)(ws + 8 * MB);   // 6 MB
    unsigned short* Wot  = (unsigned short*)(ws + 14 * MB);  // 2 MB
    unsigned short* q_ws = (unsigned short*)(ws + 16 * MB);  // 8 MB
    unsigned short* k_ws = (unsigned short*)(ws + 24 * MB);  // 8 MB (fragment-tiled)
    unsigned short* vt_ws= (unsigned short*)(ws + 32 * MB);  // 8 MB (fragment-tiled)

    prep<<<dim3(1536), dim3(256), 0, stream>>>(x, Wq, Wkv, Wo, xb, Wt, Wot);
    qkv_gemm2<<<dim3(768), dim3(256), 0, stream>>>(xb, Wt, q_ws, k_ws, vt_ws);
    attn_fwd8<<<dim3(1024), dim3(128), 0, stream>>>(q_ws, k_ws, vt_ws, o2);
    out_gemm2<<<dim3(512), dim3(256), 0, stream>>>(o2, Wot, bo, out);
}

// Round 5
// 182.828 us; speedup vs baseline: 1.1518x; 1.1518x over previous
//
#include <hip/hip_runtime.h>

// B=2, N=2048, DIM=1024, HEADS=16, DHEAD=64, INNER=1024. fp32 in/out.
// prep -> qkv GEMM (16x16x32, gld16, XOR-swizzle, XCD supertile; R0 K/V
// layouts: K row-major, V [d][key]) -> attn v9 (4 waves = 2 q-groups x
// 2 key-halves; qt=2 per wave halves LDS-read redundancy vs v5; 16 iters
// halves barriers; block-internal kh-combine) -> out GEMM (XCD supertile).
// similarity ignored: softmax row-const no-op.

typedef __attribute__((ext_vector_type(8))) short short8;
typedef __attribute__((ext_vector_type(4))) float float4_;
typedef __attribute__((ext_vector_type(16))) float floatx16;
typedef __attribute__((ext_vector_type(4))) unsigned short ushort4_;
typedef __attribute__((ext_vector_type(4))) unsigned int uint4_;

#define MFMA(a, b, c) __builtin_amdgcn_mfma_f32_16x16x32_bf16((a), (b), (c), 0, 0, 0)
#define MFMA32(a, b, c) __builtin_amdgcn_mfma_f32_32x32x16_bf16((a), (b), (c), 0, 0, 0)

static __device__ __forceinline__ unsigned short f2bf(float f) {
    union { float f; unsigned int u; } v; v.f = f;
    unsigned int r = v.u + 0x7FFFu + ((v.u >> 16) & 1u);  // RNE
    return (unsigned short)(r >> 16);
}

static __device__ __forceinline__ void gld16(const void* g, void* l) {
    __builtin_amdgcn_global_load_lds(
        (__attribute__((address_space(1))) void*)(g),
        (__attribute__((address_space(3))) void*)(l), 16, 0, 0);
}

// ---------------------------------------------------------------------------
// K0 prep: blocks 0..1023 transpose+convert weights; 1024..1535 convert X.
// ---------------------------------------------------------------------------
__global__ __launch_bounds__(256) void prep(
    const float* __restrict__ X, const float* __restrict__ Wq,
    const float* __restrict__ Wkv, const float* __restrict__ Wo,
    unsigned short* __restrict__ xb, unsigned short* __restrict__ Wt,
    unsigned short* __restrict__ Wot)
{
    const int bid = blockIdx.x, t = threadIdx.x;
    if (bid >= 1024) {
        const int b = bid - 1024;
        const float4_* src = (const float4_*)X;
        ushort4_* dst = (ushort4_*)xb;
        #pragma unroll
        for (int g = 0; g < 8; ++g) {
            const int idx = b * 2048 + g * 256 + t;
            float4_ v = src[idx];
            ushort4_ o;
            o[0] = f2bf(v[0]); o[1] = f2bf(v[1]);
            o[2] = f2bf(v[2]); o[3] = f2bf(v[3]);
            dst[idx] = o;
        }
        return;
    }
    __shared__ float tile[64][65];
    const float* src; unsigned short* dst; int N, kt, nt, drow0;
    if (bid < 256)      { src = Wq;  N = 1024; kt = bid & 15;       nt = bid >> 4;       dst = Wt;  drow0 = nt * 64; }
    else if (bid < 768) { src = Wkv; N = 2048; kt = (bid-256) & 15; nt = (bid-256) >> 4; dst = Wt;  drow0 = 1024 + nt * 64; }
    else                { src = Wo;  N = 1024; kt = (bid-768) & 15; nt = (bid-768) >> 4; dst = Wot; drow0 = nt * 64; }
    const int k0 = kt * 64, n0 = nt * 64;
    const int r0 = t >> 6, c = t & 63;
    #pragma unroll
    for (int i = 0; i < 16; ++i) {
        const int r = i * 4 + r0;
        tile[r][c] = src[(size_t)(k0 + r) * N + n0 + c];
    }
    __syncthreads();
    #pragma unroll
    for (int i = 0; i < 16; ++i) {
        const int rn = i * 4 + r0;
        dst[(size_t)(drow0 + rn) * 1024 + k0 + c] = f2bf(tile[c][rn]);
    }
}

// ---------------------------------------------------------------------------
// K1: QKV = xb @ Wt^T. 128x128 tile, gld16 + XOR swizzle. XCD supertile.
// R0 epilogue layouts: Q row-major (scaled), K row-major, V^T [d][key].
// ---------------------------------------------------------------------------
__global__ __launch_bounds__(256) void qkv_gemm2(
    const unsigned short* __restrict__ xb, const unsigned short* __restrict__ Wt,
    unsigned short* __restrict__ q_ws, unsigned short* __restrict__ k_ws,
    unsigned short* __restrict__ vt_ws)
{
    __shared__ unsigned short As[128 * 64];
    __shared__ unsigned short Bs[128 * 64];
    const int t = threadIdx.x, wave = t >> 6, lane = t & 63;
    const int L = lane & 15, quad = lane >> 4;
    const int xcd = blockIdx.x & 7, idx = blockIdx.x >> 3;
    const int mb = (xcd >> 1) * 8 + (idx & 7);
    const int nb = (xcd & 1) * 12 + (idx >> 3);
    const int m0 = mb * 128, n0 = nb * 128;
    const int wr = wave >> 1, wc = wave & 1;

    float4_ z = {0.f, 0.f, 0.f, 0.f};
    float4_ acc[4][4];
    #pragma unroll
    for (int i = 0; i < 4; ++i)
        #pragma unroll
        for (int j = 0; j < 4; ++j) acc[i][j] = z;

    const unsigned short* gA[4]; const unsigned short* gB[4];
    unsigned short* lA[4]; unsigned short* lB[4];
    #pragma unroll
    for (int j = 0; j < 4; ++j) {
        const int cid = wave * 256 + j * 64 + lane;
        const int row = cid >> 3, pc = cid & 7;
        const int lch = pc ^ (row & 7);
        gA[j] = xb + (size_t)(m0 + row) * 1024 + lch * 8;
        gB[j] = Wt + (size_t)(n0 + row) * 1024 + lch * 8;
        lA[j] = As + wave * 2048 + j * 512;
        lB[j] = Bs + wave * 2048 + j * 512;
    }

    for (int kc = 0; kc < 1024; kc += 64) {
        #pragma unroll
        for (int j = 0; j < 4; ++j) {
            gld16(gA[j] + kc, lA[j]);
            gld16(gB[j] + kc, lB[j]);
        }
        __syncthreads();
        #pragma unroll
        for (int ks = 0; ks < 2; ++ks) {
            short8 af[4], bfr[4];
            #pragma unroll
            for (int mt = 0; mt < 4; ++mt) {
                const int rl = wr * 64 + mt * 16 + L;
                af[mt] = *(const short8*)(As + rl * 64 + (((ks * 4 + quad) ^ (L & 7)) << 3));
            }
            #pragma unroll
            for (int nt = 0; nt < 4; ++nt) {
                const int rl = wc * 64 + nt * 16 + L;
                bfr[nt] = *(const short8*)(Bs + rl * 64 + (((ks * 4 + quad) ^ (L & 7)) << 3));
            }
            #pragma unroll
            for (int mt = 0; mt < 4; ++mt)
                #pragma unroll
                for (int nt = 0; nt < 4; ++nt)
                    acc[mt][nt] = MFMA(af[mt], bfr[nt], acc[mt][nt]);
        }
        __syncthreads();
    }

    const int b = m0 >> 11;
    const int type = n0 >> 10;  // 0=Q, 1=K, 2=V
    #pragma unroll
    for (int mt = 0; mt < 4; ++mt) {
        const int m = (m0 & 2047) + wr * 64 + mt * 16 + quad * 4;
        #pragma unroll
        for (int nt = 0; nt < 4; ++nt) {
            const int cl = (n0 & 1023) + wc * 64 + nt * 16 + L;
            const int h = cl >> 6, d = cl & 63;
            float4_ v = acc[mt][nt];
            if (type == 0) {
                // fold 0.125 softmax scale and log2(e): exp(x)=exp2(x*log2e)
                unsigned short* p = q_ws + ((size_t)(b * 16 + h) * 2048 + m) * 64 + d;
                #pragma unroll
                for (int r = 0; r < 4; ++r) p[(size_t)r * 64] = f2bf(v[r] * 0.18033688011f);
            } else if (type == 1) {
                unsigned short* p = k_ws + ((size_t)(b * 16 + h) * 2048 + m) * 64 + d;
                #pragma unroll
                for (int r = 0; r < 4; ++r) p[(size_t)r * 64] = f2bf(v[r]);
            } else {
                ushort4_ pk;
                pk[0] = f2bf(v[0]); pk[1] = f2bf(v[1]);
                pk[2] = f2bf(v[2]); pk[3] = f2bf(v[3]);
                *(ushort4_*)(vt_ws + ((size_t)(b * 16 + h) * 64 + d) * 2048 + m) = pk;
            }
        }
    }
}

// ---------------------------------------------------------------------------
// K2 v9: flash attention, qt=2 + key-split waves. 512 blocks x 256 threads.
// Block = (bh, 128 q-rows). Wave w: q-group qg=w&1 (64 rows), key-half
// kh=w>>1 (1024 keys, 16 iters of 64). Each wave reads its kh's K/V LDS tile
// once per iter, amortized over 64 q-rows (2x less LDS traffic than v5) and
// 16 barriers (2x fewer). kh-partials combined block-internally via LDS
// (exact: no running max needed). Staging/compute body verbatim from v5
// (pi bit2<->bit3 K-row perm + XOR swizzle); combine pattern from v7.
// ---------------------------------------------------------------------------
__global__ __launch_bounds__(256, 2) void attn_fwd9(
    const unsigned short* __restrict__ q_ws,
    const unsigned short* __restrict__ k_ws,
    const unsigned short* __restrict__ vt_ws,
    unsigned short* __restrict__ o2)
{
    // pool: K tiles [kh][p][4096 sh] @ 0..16383, V tiles @ 16384..32767.
    // combine buffer (f32) aliases shorts 0..16383 (32 KB) after last K read.
    __shared__ unsigned short pool[32768];
    __shared__ float lsd[2][2][2][32];  // [kh][qg][qt][l32]
    const int t = threadIdx.x, wave = t >> 6, lane = t & 63;
    const int l32 = lane & 31, hi = lane >> 5;
    const int qg = wave & 1, kh = wave >> 1;
    const int xcd = blockIdx.x & 7, loc = blockIdx.x >> 3;
    const int bh = xcd * 4 + (loc >> 4);
    const int qb = loc & 15;

    const unsigned short* Kp = k_ws + (size_t)bh * 2048 * 64;
    const unsigned short* Vt = vt_ws + (size_t)bh * 64 * 2048;

    // Q fragments: 64 q-rows per wave (qt=2), 8 short8.
    short8 qf[2][4];
    #pragma unroll
    for (int qt = 0; qt < 2; ++qt) {
        const unsigned short* Qp = q_ws
            + ((size_t)(bh * 2048 + qb * 128 + qg * 64 + qt * 32 + l32)) * 64 + hi * 8;
        #pragma unroll
        for (int k = 0; k < 4; ++k) qf[qt][k] = *(const short8*)(Qp + k * 16);
    }

    // Staging sources (per-lane, pre-swizzled) + LDS dests (wave-uniform).
    // cid = g*128 + qg*64 + lane covers chunks 0..511 of the 8KB tile per
    // kh-group; kr=cid>>3 (row), kl=(cid&7)^(kr&7) (XOR slot), pi on K rows.
    const unsigned short* kg[4]; const unsigned short* vg[4];
    unsigned short* kdst[4]; unsigned short* vdst[4];
    #pragma unroll
    for (int g = 0; g < 4; ++g) {
        const int cid = g * 128 + qg * 64 + lane;
        const int kr = cid >> 3;
        const int kl = (cid & 7) ^ (kr & 7);
        const int pr = (kr & ~12) | ((kr & 4) << 1) | ((kr & 8) >> 1);  // pi
        kg[g] = Kp + (size_t)(kh * 1024 + pr) * 64 + kl * 8;
        vg[g] = Vt + (size_t)kr * 2048 + kh * 1024 + kl * 8;
        kdst[g] = pool + kh * 8192 + g * 1024 + qg * 512;
        vdst[g] = pool + 16384 + kh * 8192 + g * 1024 + qg * 512;
    }

#define STAGE9(p_, it_) do {                                                  \
    const int ko_ = (it_) * 4096; /* 64 key-rows * 64 d */                    \
    const int vo_ = (it_) * 64;   /* 64 keys along V rows */                  \
    _Pragma("unroll")                                                         \
    for (int g = 0; g < 4; ++g) gld16(kg[g] + ko_, kdst[g] + (p_) * 4096);    \
    _Pragma("unroll")                                                         \
    for (int g = 0; g < 4; ++g) gld16(vg[g] + vo_, vdst[g] + (p_) * 4096);    \
} while (0)

    floatx16 o00, o01, o10, o11;
    #pragma unroll
    for (int r = 0; r < 16; ++r) { o00[r] = 0.f; o01[r] = 0.f; o10[r] = 0.f; o11[r] = 0.f; }
    float lsum0 = 0.f, lsum1 = 0.f;

    STAGE9(0, 0);
    __syncthreads();
    const int sw = l32 & 7;

    #pragma unroll 1
    for (int it = 0; it < 16; ++it) {
        const int p = it & 1;
        if (it + 1 < 16) STAGE9(p ^ 1, it + 1);
        const unsigned short* kb = pool + kh * 8192 + p * 4096;
        const unsigned short* vb = pool + 16384 + kh * 8192 + p * 4096;

        // QK^T: S[key][q] for both qt, both key-sub-halves. K frags shared.
        floatx16 s00, s01, s10, s11;
        #pragma unroll
        for (int r = 0; r < 16; ++r) { s00[r] = 0.f; s01[r] = 0.f; s10[r] = 0.f; s11[r] = 0.f; }
        #pragma unroll
        for (int k = 0; k < 4; ++k) {
            const int off = (((2 * k + hi) ^ sw) << 3);
            short8 k0 = *(const short8*)(kb + l32 * 64 + off);
            short8 k1 = *(const short8*)(kb + (32 + l32) * 64 + off);
            s00 = MFMA32(k0, qf[0][k], s00); s01 = MFMA32(k1, qf[0][k], s01);
            s10 = MFMA32(k0, qf[1][k], s10); s11 = MFMA32(k1, qf[1][k], s11);
        }

        // exp2 + byte-pack to bf16 (v5 verbatim), per qt.
        unsigned int pkA0[8], pkA1[8], pkB0[8], pkB1[8];
        #pragma unroll
        for (int d = 0; d < 8; ++d) {
            union { float f; unsigned int u; } a0, b0, a1, b1;
            a0.f = __builtin_amdgcn_exp2f(s00[2 * d]);
            b0.f = __builtin_amdgcn_exp2f(s00[2 * d + 1]);
            a1.f = __builtin_amdgcn_exp2f(s01[2 * d]);
            b1.f = __builtin_amdgcn_exp2f(s01[2 * d + 1]);
            lsum0 += (a0.f + b0.f) + (a1.f + b1.f);
            pkA0[d] = __builtin_amdgcn_perm(b0.u, a0.u, 0x07060302u);
            pkA1[d] = __builtin_amdgcn_perm(b1.u, a1.u, 0x07060302u);
        }
        #pragma unroll
        for (int d = 0; d < 8; ++d) {
            union { float f; unsigned int u; } a0, b0, a1, b1;
            a0.f = __builtin_amdgcn_exp2f(s10[2 * d]);
            b0.f = __builtin_amdgcn_exp2f(s10[2 * d + 1]);
            a1.f = __builtin_amdgcn_exp2f(s11[2 * d]);
            b1.f = __builtin_amdgcn_exp2f(s11[2 * d + 1]);
            lsum1 += (a0.f + b0.f) + (a1.f + b1.f);
            pkB0[d] = __builtin_amdgcn_perm(b0.u, a0.u, 0x07060302u);
            pkB1[d] = __builtin_amdgcn_perm(b1.u, a1.u, 0x07060302u);
        }

        // PV: V frags shared across qt.
        #pragma unroll
        for (int w = 0; w < 4; ++w) {
            const int c = 2 * w + hi;
            const int voff = ((c ^ sw) << 3);
            short8 vf0 = *(const short8*)(vb + l32 * 64 + voff);
            short8 vf1 = *(const short8*)(vb + (32 + l32) * 64 + voff);
            uint4_ pwA, pwB;
            if (w == 0)      { pwA[0]=pkA0[0]; pwA[1]=pkA0[1]; pwA[2]=pkA0[2]; pwA[3]=pkA0[3];
                               pwB[0]=pkB0[0]; pwB[1]=pkB0[1]; pwB[2]=pkB0[2]; pwB[3]=pkB0[3]; }
            else if (w == 1) { pwA[0]=pkA0[4]; pwA[1]=pkA0[5]; pwA[2]=pkA0[6]; pwA[3]=pkA0[7];
                               pwB[0]=pkB0[4]; pwB[1]=pkB0[5]; pwB[2]=pkB0[6]; pwB[3]=pkB0[7]; }
            else if (w == 2) { pwA[0]=pkA1[0]; pwA[1]=pkA1[1]; pwA[2]=pkA1[2]; pwA[3]=pkA1[3];
                               pwB[0]=pkB1[0]; pwB[1]=pkB1[1]; pwB[2]=pkB1[2]; pwB[3]=pkB1[3]; }
            else             { pwA[0]=pkA1[4]; pwA[1]=pkA1[5]; pwA[2]=pkA1[6]; pwA[3]=pkA1[7];
                               pwB[0]=pkB1[4]; pwB[1]=pkB1[5]; pwB[2]=pkB1[6]; pwB[3]=pkB1[7]; }
            short8 paA = *(short8*)&pwA;
            short8 paB = *(short8*)&pwB;
            o00 = MFMA32(paA, vf0, o00); o01 = MFMA32(paA, vf1, o01);
            o10 = MFMA32(paB, vf0, o10); o11 = MFMA32(paB, vf1, o11);
        }
        __syncthreads();
    }

    // Row sums across the wave's 1024 keys (both key-sub-halves via xor-32).
    const float lt0 = lsum0 + __shfl_xor(lsum0, 32);
    const float lt1 = lsum1 + __shfl_xor(lsum1, 32);
    lsd[kh][qg][0][l32] = lt0;
    lsd[kh][qg][1][l32] = lt1;

    // kh=1 waves donate O-partials via LDS (aliases K region; safe after the
    // loop's final barrier). kh=0 waves add, normalize, store.
    float* cb = (float*)pool;
    if (kh == 1) {
        float* base = cb + qg * 4096;
        #pragma unroll
        for (int r = 0; r < 16; ++r) {
            base[(0 * 16 + r) * 64 + lane] = o00[r];
            base[(1 * 16 + r) * 64 + lane] = o01[r];
            base[(2 * 16 + r) * 64 + lane] = o10[r];
            base[(3 * 16 + r) * 64 + lane] = o11[r];
        }
    }
    __syncthreads();
    if (kh == 0) {
        const int b = bh >> 4, h = bh & 15;
        const float* base = cb + qg * 4096;
        unsigned short* obase = o2
            + ((size_t)(b * 2048 + qb * 128 + qg * 64)) * 1024 + h * 64;
        #pragma unroll
        for (int r = 0; r < 16; ++r) {
            const int rowloc = (r & 3) + 8 * (r >> 2) + 4 * hi;
            const float i0 = 1.0f / (lsd[0][qg][0][rowloc] + lsd[1][qg][0][rowloc]);
            const float i1 = 1.0f / (lsd[0][qg][1][rowloc] + lsd[1][qg][1][rowloc]);
            const float a0 = o00[r] + base[(0 * 16 + r) * 64 + lane];
            const float a1 = o01[r] + base[(1 * 16 + r) * 64 + lane];
            const float b0 = o10[r] + base[(2 * 16 + r) * 64 + lane];
            const float b1 = o11[r] + base[(3 * 16 + r) * 64 + lane];
            obase[(size_t)rowloc * 1024 + l32]             = f2bf(a0 * i0);
            obase[(size_t)rowloc * 1024 + 32 + l32]        = f2bf(a1 * i0);
            obase[(size_t)(32 + rowloc) * 1024 + l32]      = f2bf(b0 * i1);
            obase[(size_t)(32 + rowloc) * 1024 + 32 + l32] = f2bf(b1 * i1);
        }
    }
#undef STAGE9
}

// ---------------------------------------------------------------------------
// K3: Out = o2 @ Wot^T + bo (fp32 out). 128x64 tile. XCD supertile.
// ---------------------------------------------------------------------------
__global__ __launch_bounds__(256) void out_gemm2(
    const unsigned short* __restrict__ o2, const unsigned short* __restrict__ Wot,
    const float* __restrict__ bo, float* __restrict__ Out)
{
    __shared__ unsigned short As[128 * 64];
    __shared__ unsigned short Bs[64 * 64];
    const int t = threadIdx.x, wave = t >> 6, lane = t & 63;
    const int L = lane & 15, quad = lane >> 4;
    const int xcd = blockIdx.x & 7, idx = blockIdx.x >> 3;
    const int mb = (xcd >> 1) * 8 + (idx & 7);
    const int nb = (xcd & 1) * 8 + (idx >> 3);
    const int m0 = mb * 128, n0 = nb * 64;
    const int wr = wave >> 1, wc = wave & 1;

    float4_ z = {0.f, 0.f, 0.f, 0.f};
    float4_ acc[4][2];
    #pragma unroll
    for (int i = 0; i < 4; ++i)
        #pragma unroll
        for (int j = 0; j < 2; ++j) acc[i][j] = z;

    const unsigned short* gA[4]; unsigned short* lA[4];
    #pragma unroll
    for (int j = 0; j < 4; ++j) {
        const int cid = wave * 256 + j * 64 + lane;
        const int row = cid >> 3, pc = cid & 7;
        gA[j] = o2 + (size_t)(m0 + row) * 1024 + (pc ^ (row & 7)) * 8;
        lA[j] = As + wave * 2048 + j * 512;
    }
    const unsigned short* gB[2]; unsigned short* lB[2];
    #pragma unroll
    for (int j = 0; j < 2; ++j) {
        const int cid = wave * 128 + j * 64 + lane;
        const int row = cid >> 3, pc = cid & 7;
        gB[j] = Wot + (size_t)(n0 + row) * 1024 + (pc ^ (row & 7)) * 8;
        lB[j] = Bs + wave * 1024 + j * 512;
    }

    for (int kc = 0; kc < 1024; kc += 64) {
        #pragma unroll
        for (int j = 0; j < 4; ++j) gld16(gA[j] + kc, lA[j]);
        #pragma unroll
        for (int j = 0; j < 2; ++j) gld16(gB[j] + kc, lB[j]);
        __syncthreads();
        #pragma unroll
        for (int ks = 0; ks < 2; ++ks) {
            short8 af[4], bfr[2];
            #pragma unroll
            for (int mt = 0; mt < 4; ++mt) {
                const int rl = wr * 64 + mt * 16 + L;
                af[mt] = *(const short8*)(As + rl * 64 + (((ks * 4 + quad) ^ (L & 7)) << 3));
            }
            #pragma unroll
            for (int nt = 0; nt < 2; ++nt) {
                const int rl = wc * 32 + nt * 16 + L;
                bfr[nt] = *(const short8*)(Bs + rl * 64 + (((ks * 4 + quad) ^ (L & 7)) << 3));
            }
            #pragma unroll
            for (int mt = 0; mt < 4; ++mt)
                #pragma unroll
                for (int nt = 0; nt < 2; ++nt)
                    acc[mt][nt] = MFMA(af[mt], bfr[nt], acc[mt][nt]);
        }
        __syncthreads();
    }

    #pragma unroll
    for (int mt = 0; mt < 4; ++mt) {
        const int m = m0 + wr * 64 + mt * 16 + quad * 4;
        #pragma unroll
        for (int nt = 0; nt < 2; ++nt) {
            const int c = n0 + wc * 32 + nt * 16 + L;
            const float bias = bo[c];
            #pragma unroll
            for (int r = 0; r < 4; ++r)
                Out[(size_t)(m + r) * 1024 + c] = acc[mt][nt][r] + bias;
        }
    }
}

// ---------------------------------------------------------------------------
extern "C" void kernel_launch(void* const* d_in, const int* in_sizes, int n_in,
                              void* d_out, int out_size, void* d_ws, size_t ws_size,
                              hipStream_t stream) {
    const float* x   = (const float*)d_in[0];
    // d_in[1] = similarity: softmax no-op, ignored.
    const float* Wq  = (const float*)d_in[2];
    const float* Wkv = (const float*)d_in[3];
    const float* Wo  = (const float*)d_in[4];
    const float* bo  = (const float*)d_in[5];
    float* out = (float*)d_out;

    char* ws = (char*)d_ws;
    const size_t MB = 1024 * 1024;
    unsigned short* xb   = (unsigned short*)(ws);            // 8 MB; reused as o2
    unsigned short* o2   = xb;                               // alias (xb dead after K1)
    unsigned short* Wt   = (unsigned short*)(ws + 8 * MB);   // 6 MB
    unsigned short* Wot  = (unsigned short*)(ws + 14 * MB);  // 2 MB
    unsigned short* q_ws = (unsigned short*)(ws + 16 * MB);  // 8 MB
    unsigned short* k_ws = (unsigned short*)(ws + 24 * MB);  // 8 MB (row-major)
    unsigned short* vt_ws= (unsigned short*)(ws + 32 * MB);  // 8 MB ([d][key])

    prep<<<dim3(1536), dim3(256), 0, stream>>>(x, Wq, Wkv, Wo, xb, Wt, Wot);
    qkv_gemm2<<<dim3(768), dim3(256), 0, stream>>>(xb, Wt, q_ws, k_ws, vt_ws);
    attn_fwd9<<<dim3(512), dim3(256), 0, stream>>>(q_ws, k_ws, vt_ws, o2);
    out_gemm2<<<dim3(512), dim3(256), 0, stream>>>(o2, Wot, bo, out);
}